// Round 2
// baseline (255.491 us; speedup 1.0000x reference)
//
#include <hip/hip_runtime.h>
#include <hip/hip_bf16.h>

typedef __attribute__((ext_vector_type(8))) short short8;
typedef __attribute__((ext_vector_type(4))) short short4v;
typedef __attribute__((ext_vector_type(4))) unsigned short ushort4v;
typedef __attribute__((ext_vector_type(4))) float f32x4;
typedef __attribute__((ext_vector_type(16))) float f32x16;

#define NTOK 8192
#define DM 1024
#define DE 1024
#define NE 8

__device__ __forceinline__ float bf2f(unsigned short u) {
  union { unsigned int i; float f; } v; v.i = ((unsigned int)u) << 16; return v.f;
}
__device__ __forceinline__ unsigned short f2bf(float f) {
  union { float f; unsigned int i; } v; v.f = f;
  unsigned int lsb = (v.i >> 16) & 1;
  v.i += 0x7fffu + lsb;  // RNE; inputs finite
  return (unsigned short)(v.i >> 16);
}
__device__ __forceinline__ void gl_lds(const short* g, short* l) {
  __builtin_amdgcn_global_load_lds((const __attribute__((address_space(1))) void*)g,
                                   (__attribute__((address_space(3))) void*)l, 16, 0, 0);
}

// ------- W fp32 [K][N] -> bf16 transposed; W1/W3 interleaved into wcat -------
// wcat[e]: 2048 rows in 128-row groups: group g rows [g*128, g*128+64) = W1^T
//          cols g*64+[0,64); rows +64 = W3^T same cols.  (N=128 B-tile = one
//          group = 64 matched W1/W3 column pairs.)
// w2t[e]: plain W2^T [1024][1024]
__global__ __launch_bounds__(256) void k_transw(const float* __restrict__ W1,
                                                const float* __restrict__ W2,
                                                const float* __restrict__ W3,
                                                short* __restrict__ wcat,
                                                short* __restrict__ w2t) {
  __shared__ float t[64][65];
  int mid = blockIdx.z;
  const float* src;
  if (mid < 8)       src = W1 + (size_t)mid * (DM * DE);
  else if (mid < 16) src = W3 + (size_t)(mid - 8) * (DM * DE);
  else               src = W2 + (size_t)(mid - 16) * (DE * DM);
  int tid = threadIdx.x;
  int tr = tid >> 4, tc = tid & 15;
  int kbase = blockIdx.y * 64, nbase = blockIdx.x * 64;
#pragma unroll
  for (int j = 0; j < 4; j++) {
    int kr = tr + j * 16;
    f32x4 v = *(const f32x4*)(src + (size_t)(kbase + kr) * 1024 + nbase + tc * 4);
    t[kr][tc * 4 + 0] = v[0]; t[kr][tc * 4 + 1] = v[1];
    t[kr][tc * 4 + 2] = v[2]; t[kr][tc * 4 + 3] = v[3];
  }
  __syncthreads();
#pragma unroll
  for (int j = 0; j < 4; j++) {
    int n = tr + j * 16;          // source column (0..1023 within this matrix)
    int ng = nbase + n;
    short4v o;
    o[0] = (short)f2bf(t[tc * 4 + 0][n]);
    o[1] = (short)f2bf(t[tc * 4 + 1][n]);
    o[2] = (short)f2bf(t[tc * 4 + 2][n]);
    o[3] = (short)f2bf(t[tc * 4 + 3][n]);
    size_t dsto;
    if (mid < 16) {
      int e = mid & 7, p = mid >> 3;
      int row_out = ((ng >> 6) * 128) + p * 64 + (ng & 63);
      dsto = (size_t)e * (2048 * 1024) + (size_t)row_out * 1024 + kbase + tc * 4;
      *(short4v*)(wcat + dsto) = o;
    } else {
      int e = mid - 16;
      dsto = (size_t)e * (1024 * 1024) + (size_t)ng * 1024 + kbase + tc * 4;
      *(short4v*)(w2t + dsto) = o;
    }
  }
}

// ------- router: fp32 logits, softmax-top2, fused x->bf16 conversion -------
__global__ __launch_bounds__(256) void k_router(const float* __restrict__ x,
                                                const float* __restrict__ Wr,
                                                short* __restrict__ xb,
                                                int* __restrict__ esel,
                                                float* __restrict__ wgt) {
  int wid = threadIdx.x >> 6, lane = threadIdx.x & 63;
  int t = blockIdx.x * 4 + wid;
  const float* xr = x + (size_t)t * DM;
  float acc[8];
#pragma unroll
  for (int e = 0; e < 8; e++) acc[e] = 0.f;
#pragma unroll
  for (int i = 0; i < 4; i++) {
    int kb = (i * 64 + lane) * 4;
    f32x4 v = *(const f32x4*)(xr + kb);
    ushort4v ob;
#pragma unroll
    for (int j = 0; j < 4; j++) {
      f32x4 w0 = *(const f32x4*)(Wr + (size_t)(kb + j) * 8);
      f32x4 w1 = *(const f32x4*)(Wr + (size_t)(kb + j) * 8 + 4);
      float xv = v[j];
      ob[j] = f2bf(xv);
      acc[0] += xv * w0[0]; acc[1] += xv * w0[1];
      acc[2] += xv * w0[2]; acc[3] += xv * w0[3];
      acc[4] += xv * w1[0]; acc[5] += xv * w1[1];
      acc[6] += xv * w1[2]; acc[7] += xv * w1[3];
    }
    *(ushort4v*)(xb + (size_t)t * DM + kb) = ob;
  }
#pragma unroll
  for (int off = 32; off; off >>= 1)
#pragma unroll
    for (int e = 0; e < 8; e++) acc[e] += __shfl_xor(acc[e], off);
  float m0 = -1e30f, m1 = -1e30f; int e0 = 0, e1 = 0;
#pragma unroll
  for (int e = 0; e < 8; e++) {
    float v = acc[e];
    if (v > m0) { m1 = m0; e1 = e0; m0 = v; e0 = e; }
    else if (v > m1) { m1 = v; e1 = e; }
  }
  float p = __expf(m1 - m0);
  if (lane == 0) {
    esel[2 * t] = e0; esel[2 * t + 1] = e1;
    wgt[2 * t] = 1.f / (1.f + p); wgt[2 * t + 1] = p / (1.f + p);
  }
}

// ---- ranks via wave ballots + per-block aggregated atomics ----
__global__ __launch_bounds__(256) void k_rank(const int* __restrict__ esel,
                                              int* __restrict__ cnt,
                                              int* __restrict__ rank) {
  __shared__ int wcnt[4][8];
  __shared__ int woff[4][8];
  int tid = threadIdx.x;
  int lane = tid & 63, wid = tid >> 6;
  int t = blockIdx.x * 256 + tid;
  int e0 = esel[2 * t], e1 = esel[2 * t + 1];
  unsigned long long lt = (lane == 0) ? 0ull : ((~0ull) >> (64 - lane));
  int r0 = 0, r1 = 0;
#pragma unroll
  for (int e = 0; e < 8; e++) {
    unsigned long long m0 = __ballot(e0 == e);
    unsigned long long m1 = __ballot(e1 == e);
    int c0 = __popcll(m0);
    if (e0 == e) r0 = __popcll(m0 & lt);
    if (e1 == e) r1 = c0 + __popcll(m1 & lt);
    if (lane == 0) wcnt[wid][e] = c0 + __popcll(m1);
  }
  __syncthreads();
  if (tid < 8) {
    int e = tid;
    int c0 = wcnt[0][e], c1 = wcnt[1][e], c2 = wcnt[2][e], c3 = wcnt[3][e];
    int base = atomicAdd(&cnt[e], c0 + c1 + c2 + c3);
    woff[0][e] = base;
    woff[1][e] = base + c0;
    woff[2][e] = base + c0 + c1;
    woff[3][e] = base + c0 + c1 + c2;
  }
  __syncthreads();
  rank[2 * t] = woff[wid][e0] + r0;
  rank[2 * t + 1] = woff[wid][e1] + r1;
}

__global__ void k_offsets(const int* __restrict__ cnt, int* __restrict__ off) {
  if (threadIdx.x == 0) {
    int s = 0;
    for (int e = 0; e < NE; e++) { off[e] = s; s += cnt[e]; }
  }
}

__global__ __launch_bounds__(256) void k_scatter(const int* __restrict__ off,
                                                 const int* __restrict__ esel,
                                                 const int* __restrict__ rank,
                                                 int* __restrict__ tok_of_slot,
                                                 int* __restrict__ slot_of_tok) {
  int t = blockIdx.x * 256 + threadIdx.x;
#pragma unroll
  for (int j = 0; j < 2; j++) {
    int e = esel[2 * t + j];
    int s = off[e] + rank[2 * t + j];
    tok_of_slot[s] = t;
    slot_of_tok[2 * t + j] = s;
  }
}

// ============ 256x128-tile BK=32 grouped GEMM, 3-ring counted-vmcnt ============
// 2 blocks/CU (LDS 72KB, regs 124/wave via launch_bounds(512,4)).
// 8 waves = 4 (wr, M) x 2 (wcn, N); wave tile 64x64 via 2x2 frags of
// v_mfma_f32_32x32x16_bf16 (8 MFMA/wave/k-tile, acc = 4x f32x16 = 64 regs).
// Single barrier per k-tile: with the 3-ring, the buffer written at tile t was
// last read at t-1; end-of-(t-1) barrier (after each wave's lgkmcnt drain
// before its MFMAs) guarantees those reads retired. vmcnt(3) precedes the
// barrier so all waves' tile-(t+1) staging has landed before anyone reads it.
// FFN1=1: A = xb gathered via tok_of_slot, B = wcat group (64 W1 + 64 W3 col
//         pairs; frag n=0 = W1 rows, n=1 = W3 rows, same 32 cols -> silu
//         pairing lane-local), epilogue silu(a1)*a3 -> h (64 cols/blk)
// FFN1=0: A = h (slot rows), B = w2t, epilogue -> y (128 cols/blk)
template<int FFN1>
__global__ __launch_bounds__(512, 4) void k_ffn(const short* __restrict__ Abase,
                                                const short* __restrict__ Bbase,
                                                const int* __restrict__ cnt,
                                                const int* __restrict__ off,
                                                const int* __restrict__ tok_of_slot,
                                                short* __restrict__ outp) {
  const int e = blockIdx.y;
  const int cnt_e = cnt[e];
  const int m0 = blockIdx.z * 256;
  if (m0 >= cnt_e) return;
  const int bse = off[e];
  const int n0 = blockIdx.x * 128;
  const short* Bt = Bbase + (size_t)e * ((FFN1 ? 2048 : 1024) * 1024) + (size_t)n0 * 1024;

  // one k-tile: A 256x32 bf16 = 16 KB (8192 shorts), B 128x32 = 8 KB (4096)
  __shared__ __align__(128) short Al[3][8192];  // 48 KB
  __shared__ __align__(128) short Bl[3][4096];  // 24 KB  (72 KB total/block)

  const int tid = threadIdx.x;
  const int lane = tid & 63, wid = tid >> 6;
  const int wr = wid >> 1, wcn = wid & 1;

  // staging sources: chunk ch; row r = ch>>2; src col-chunk
  // c = (ch&3) ^ ((r>>1)&3)  (inverse-swizzled source, linear LDS dest)
  const short* srcA0; const short* srcA1; const short* srcB0;
  {
    int r0 = tid >> 2, c0 = (tid & 3) ^ ((r0 >> 1) & 3);
    int row0 = m0 + r0; if (row0 >= cnt_e) row0 = cnt_e - 1;
    long ar0 = FFN1 ? (long)tok_of_slot[bse + row0] : (long)(bse + row0);
    srcA0 = Abase + ar0 * 1024 + c0 * 8;
    int ch1 = tid + 512;
    int r1 = ch1 >> 2, c1 = (ch1 & 3) ^ ((r1 >> 1) & 3);
    int row1 = m0 + r1; if (row1 >= cnt_e) row1 = cnt_e - 1;
    long ar1 = FFN1 ? (long)tok_of_slot[bse + row1] : (long)(bse + row1);
    srcA1 = Abase + ar1 * 1024 + c1 * 8;
    srcB0 = Bt + (size_t)r0 * 1024 + c0 * 8;   // r0 < 128 for tid < 512
  }
  const int lA0 = wid * 512, lA1 = wid * 512 + 4096, lB0 = wid * 512;

  // fragment LDS byte offsets (swizzled read side), 32x32x16 frags
  // A frag (m, ks): row = wr*64 + m*32 + (lane&31), chunk = ks*2 + (lane>>5)
  int aoff[4], boff[4];
#pragma unroll
  for (int m = 0; m < 2; m++)
#pragma unroll
    for (int ks = 0; ks < 2; ks++) {
      int r = wr * 64 + m * 32 + (lane & 31);
      int ch = ks * 2 + (lane >> 5);
      aoff[m * 2 + ks] = (r * 4 + (ch ^ ((r >> 1) & 3))) * 16;
    }
#pragma unroll
  for (int n = 0; n < 2; n++)
#pragma unroll
    for (int ks = 0; ks < 2; ks++) {
      int rb = FFN1 ? ((n ? 64 : 0) + wcn * 32 + (lane & 31))
                    : (wcn * 64 + n * 32 + (lane & 31));
      int ch = ks * 2 + (lane >> 5);
      boff[n * 2 + ks] = (rb * 4 + (ch ^ ((rb >> 1) & 3))) * 16;
    }

  f32x16 acc[2][2];
#pragma unroll
  for (int m = 0; m < 2; m++)
#pragma unroll
    for (int n = 0; n < 2; n++) acc[m][n] = (f32x16)(0.f);

#define STG_A(b, kt) { gl_lds(srcA0 + (kt) * 32, &Al[b][lA0]); \
                       gl_lds(srcA1 + (kt) * 32, &Al[b][lA1]); }
#define STG_B(b, kt) { gl_lds(srcB0 + (kt) * 32, &Bl[b][lB0]); }

  // prologue: tiles 0,1 issued (3 loads each); wait tile 0 (tile 1 in flight)
  STG_A(0, 0); STG_B(0, 0);
  STG_A(1, 1); STG_B(1, 1);
  asm volatile("s_waitcnt vmcnt(3)" ::: "memory");
  __builtin_amdgcn_s_barrier();

  int cur = 0, nxt = 2;
  for (int t = 0; t < 32; ++t) {
    int ktn = (t + 2 < 32) ? (t + 2) : 31;  // clamped dup-stage: same bytes, benign
    const char* Ab = (const char*)Al[cur];
    const char* Bb = (const char*)Bl[cur];
    short8 a[4], b[4];
#pragma unroll
    for (int i = 0; i < 4; i++) a[i] = *(const short8*)(Ab + aoff[i]);
#pragma unroll
    for (int i = 0; i < 4; i++) b[i] = *(const short8*)(Bb + boff[i]);
    STG_A(nxt, ktn); STG_B(nxt, ktn);
    __builtin_amdgcn_s_setprio(1);
#pragma unroll
    for (int ks = 0; ks < 2; ks++)
#pragma unroll
      for (int m = 0; m < 2; m++)
#pragma unroll
        for (int n = 0; n < 2; n++)
          acc[m][n] = __builtin_amdgcn_mfma_f32_32x32x16_bf16(
              a[m * 2 + ks], b[n * 2 + ks], acc[m][n], 0, 0, 0);
    __builtin_amdgcn_s_setprio(0);
    asm volatile("s_waitcnt vmcnt(3)" ::: "memory");  // tile t+1 arrived; t+2 in flight
    __builtin_amdgcn_s_barrier();
    cur = (cur == 2) ? 0 : cur + 1;
    nxt = (nxt == 2) ? 0 : nxt + 1;
  }
  asm volatile("s_waitcnt vmcnt(0)" ::: "memory");  // drain before LDS dealloc

  // ---- epilogue ----
  // 32x32 C/D layout: col = lane&31, row = (reg&3) + 8*(reg>>2) + 4*(lane>>5)
  if (FFN1) {
#pragma unroll
    for (int m = 0; m < 2; m++) {
      f32x16 v1 = acc[m][0], v3 = acc[m][1];
      int col = blockIdx.x * 64 + wcn * 32 + (lane & 31);
#pragma unroll
      for (int r = 0; r < 16; r++) {
        int row = m0 + wr * 64 + m * 32 + 4 * (lane >> 5) + (r & 3) + 8 * (r >> 2);
        if (row < cnt_e) {
          float a1v = v1[r];
          float hv = (a1v / (1.f + __expf(-a1v))) * v3[r];
          outp[(size_t)(bse + row) * DE + col] = (short)f2bf(hv);
        }
      }
    }
  } else {
#pragma unroll
    for (int m = 0; m < 2; m++)
#pragma unroll
      for (int n = 0; n < 2; n++) {
        f32x16 v = acc[m][n];
        int col = n0 + wcn * 64 + n * 32 + (lane & 31);
#pragma unroll
        for (int r = 0; r < 16; r++) {
          int row = m0 + wr * 64 + m * 32 + 4 * (lane >> 5) + (r & 3) + 8 * (r >> 2);
          if (row < cnt_e)
            outp[(size_t)(bse + row) * DM + col] = (short)f2bf(v[r]);
        }
      }
  }
}

// ---------------- combine: out[t] = w0*y[s0] + w1*y[s1] ----------------
__global__ __launch_bounds__(256) void k_combine(const short* __restrict__ y,
                                                 const int* __restrict__ slot_of_tok,
                                                 const float* __restrict__ wgt,
                                                 float* __restrict__ out) {
  int t = blockIdx.x;
  int s0 = slot_of_tok[2 * t], s1 = slot_of_tok[2 * t + 1];
  float w0 = wgt[2 * t], w1 = wgt[2 * t + 1];
  int c = threadIdx.x * 4;
  short4v a = *(const short4v*)(y + (size_t)s0 * DM + c);
  short4v b = *(const short4v*)(y + (size_t)s1 * DM + c);
  f32x4 o;
#pragma unroll
  for (int j = 0; j < 4; j++)
    o[j] = w0 * bf2f((unsigned short)a[j]) + w1 * bf2f((unsigned short)b[j]);
  *(f32x4*)(out + (size_t)t * DM + c) = o;
}

extern "C" void kernel_launch(void* const* d_in, const int* in_sizes, int n_in,
                              void* d_out, int out_size, void* d_ws, size_t ws_size,
                              hipStream_t stream) {
  const float* x  = (const float*)d_in[0];
  const float* Wr = (const float*)d_in[1];
  const float* W1 = (const float*)d_in[2];
  const float* W2 = (const float*)d_in[3];
  const float* W3 = (const float*)d_in[4];
  float* out = (float*)d_out;
  char* ws = (char*)d_ws;

  short* xb   = (short*)(ws);                   // 16 MB
  short* wcat = (short*)(ws + 16777216);        // 32 MB (8 x 2048 x 1024 bf16)
  short* w2t  = (short*)(ws + 50331648);        // 16 MB
  short* h    = (short*)(ws + 67108864);        // 32 MB
  short* y    = (short*)(ws + 100663296);       // 32 MB
  char* meta = ws + 134217728;
  int* cnt          = (int*)(meta);
  int* off          = (int*)(meta + 256);
  int* esel         = (int*)(meta + 512);
  int* rank         = (int*)(meta + 512 + 65536);
  int* tok_of_slot  = (int*)(meta + 512 + 2 * 65536);
  int* slot_of_tok  = (int*)(meta + 512 + 3 * 65536);
  float* wgt        = (float*)(meta + 512 + 4 * 65536);

  hipMemsetAsync(cnt, 0, 32, stream);
  k_transw<<<dim3(16, 16, 24), 256, 0, stream>>>(W1, W2, W3, wcat, w2t);
  k_router<<<2048, 256, 0, stream>>>(x, Wr, xb, esel, wgt);
  k_rank<<<32, 256, 0, stream>>>(esel, cnt, rank);
  k_offsets<<<1, 64, 0, stream>>>(cnt, off);
  k_scatter<<<32, 256, 0, stream>>>(off, esel, rank, tok_of_slot, slot_of_tok);
  k_ffn<1><<<dim3(16, 8, 32), 512, 0, stream>>>(xb, wcat, cnt, off, tok_of_slot, h);
  k_ffn<0><<<dim3(8, 8, 32), 512, 0, stream>>>(h, w2t, cnt, off, tok_of_slot, y);
  k_combine<<<8192, 256, 0, stream>>>(y, slot_of_tok, wgt, out);
}

// Round 3
// 237.416 us; speedup vs baseline: 1.0761x; 1.0761x over previous
//
#include <hip/hip_runtime.h>
#include <hip/hip_bf16.h>

typedef __attribute__((ext_vector_type(8))) short short8;
typedef __attribute__((ext_vector_type(4))) short short4v;
typedef __attribute__((ext_vector_type(4))) unsigned short ushort4v;
typedef __attribute__((ext_vector_type(4))) float f32x4;

#define NTOK 8192
#define DM 1024
#define DE 1024
#define NE 8

__device__ __forceinline__ float bf2f(unsigned short u) {
  union { unsigned int i; float f; } v; v.i = ((unsigned int)u) << 16; return v.f;
}
__device__ __forceinline__ unsigned short f2bf(float f) {
  union { float f; unsigned int i; } v; v.f = f;
  unsigned int lsb = (v.i >> 16) & 1;
  v.i += 0x7fffu + lsb;  // RNE; inputs finite
  return (unsigned short)(v.i >> 16);
}
__device__ __forceinline__ void gl_lds(const short* g, short* l) {
  __builtin_amdgcn_global_load_lds((const __attribute__((address_space(1))) void*)g,
                                   (__attribute__((address_space(3))) void*)l, 16, 0, 0);
}

// ------- W fp32 [K][N] -> bf16 transposed; W1/W3 interleaved into wcat -------
// wcat[e]: 2048 rows in 128-row groups: group g rows [g*128, g*128+64) = W1^T
//          cols g*64+[0,64); rows +64 = W3^T same cols.
// w2t[e]: plain W2^T [1024][1024]
__global__ __launch_bounds__(256) void k_transw(const float* __restrict__ W1,
                                                const float* __restrict__ W2,
                                                const float* __restrict__ W3,
                                                short* __restrict__ wcat,
                                                short* __restrict__ w2t) {
  __shared__ float t[64][65];
  int mid = blockIdx.z;
  const float* src;
  if (mid < 8)       src = W1 + (size_t)mid * (DM * DE);
  else if (mid < 16) src = W3 + (size_t)(mid - 8) * (DM * DE);
  else               src = W2 + (size_t)(mid - 16) * (DE * DM);
  int tid = threadIdx.x;
  int tr = tid >> 4, tc = tid & 15;
  int kbase = blockIdx.y * 64, nbase = blockIdx.x * 64;
#pragma unroll
  for (int j = 0; j < 4; j++) {
    int kr = tr + j * 16;
    f32x4 v = *(const f32x4*)(src + (size_t)(kbase + kr) * 1024 + nbase + tc * 4);
    t[kr][tc * 4 + 0] = v[0]; t[kr][tc * 4 + 1] = v[1];
    t[kr][tc * 4 + 2] = v[2]; t[kr][tc * 4 + 3] = v[3];
  }
  __syncthreads();
#pragma unroll
  for (int j = 0; j < 4; j++) {
    int n = tr + j * 16;          // source column (0..1023 within this matrix)
    int ng = nbase + n;
    short4v o;
    o[0] = (short)f2bf(t[tc * 4 + 0][n]);
    o[1] = (short)f2bf(t[tc * 4 + 1][n]);
    o[2] = (short)f2bf(t[tc * 4 + 2][n]);
    o[3] = (short)f2bf(t[tc * 4 + 3][n]);
    size_t dsto;
    if (mid < 16) {
      int e = mid & 7, p = mid >> 3;
      int row_out = ((ng >> 6) * 128) + p * 64 + (ng & 63);
      dsto = (size_t)e * (2048 * 1024) + (size_t)row_out * 1024 + kbase + tc * 4;
      *(short4v*)(wcat + dsto) = o;
    } else {
      int e = mid - 16;
      dsto = (size_t)e * (1024 * 1024) + (size_t)ng * 1024 + kbase + tc * 4;
      *(short4v*)(w2t + dsto) = o;
    }
  }
}

// ------- router: fp32 logits, softmax-top2, fused x->bf16 conversion -------
__global__ __launch_bounds__(256) void k_router(const float* __restrict__ x,
                                                const float* __restrict__ Wr,
                                                short* __restrict__ xb,
                                                int* __restrict__ esel,
                                                float* __restrict__ wgt) {
  int wid = threadIdx.x >> 6, lane = threadIdx.x & 63;
  int t = blockIdx.x * 4 + wid;
  const float* xr = x + (size_t)t * DM;
  float acc[8];
#pragma unroll
  for (int e = 0; e < 8; e++) acc[e] = 0.f;
#pragma unroll
  for (int i = 0; i < 4; i++) {
    int kb = (i * 64 + lane) * 4;
    f32x4 v = *(const f32x4*)(xr + kb);
    ushort4v ob;
#pragma unroll
    for (int j = 0; j < 4; j++) {
      f32x4 w0 = *(const f32x4*)(Wr + (size_t)(kb + j) * 8);
      f32x4 w1 = *(const f32x4*)(Wr + (size_t)(kb + j) * 8 + 4);
      float xv = v[j];
      ob[j] = f2bf(xv);
      acc[0] += xv * w0[0]; acc[1] += xv * w0[1];
      acc[2] += xv * w0[2]; acc[3] += xv * w0[3];
      acc[4] += xv * w1[0]; acc[5] += xv * w1[1];
      acc[6] += xv * w1[2]; acc[7] += xv * w1[3];
    }
    *(ushort4v*)(xb + (size_t)t * DM + kb) = ob;
  }
#pragma unroll
  for (int off = 32; off; off >>= 1)
#pragma unroll
    for (int e = 0; e < 8; e++) acc[e] += __shfl_xor(acc[e], off);
  float m0 = -1e30f, m1 = -1e30f; int e0 = 0, e1 = 0;
#pragma unroll
  for (int e = 0; e < 8; e++) {
    float v = acc[e];
    if (v > m0) { m1 = m0; e1 = e0; m0 = v; e0 = e; }
    else if (v > m1) { m1 = v; e1 = e; }
  }
  float p = __expf(m1 - m0);
  if (lane == 0) {
    esel[2 * t] = e0; esel[2 * t + 1] = e1;
    wgt[2 * t] = 1.f / (1.f + p); wgt[2 * t + 1] = p / (1.f + p);
  }
}

// ---- ranks via wave ballots + per-block aggregated atomics ----
__global__ __launch_bounds__(256) void k_rank(const int* __restrict__ esel,
                                              int* __restrict__ cnt,
                                              int* __restrict__ rank) {
  __shared__ int wcnt[4][8];
  __shared__ int woff[4][8];
  int tid = threadIdx.x;
  int lane = tid & 63, wid = tid >> 6;
  int t = blockIdx.x * 256 + tid;
  int e0 = esel[2 * t], e1 = esel[2 * t + 1];
  unsigned long long lt = (lane == 0) ? 0ull : ((~0ull) >> (64 - lane));
  int r0 = 0, r1 = 0;
#pragma unroll
  for (int e = 0; e < 8; e++) {
    unsigned long long m0 = __ballot(e0 == e);
    unsigned long long m1 = __ballot(e1 == e);
    int c0 = __popcll(m0);
    if (e0 == e) r0 = __popcll(m0 & lt);
    if (e1 == e) r1 = c0 + __popcll(m1 & lt);
    if (lane == 0) wcnt[wid][e] = c0 + __popcll(m1);
  }
  __syncthreads();
  if (tid < 8) {
    int e = tid;
    int c0 = wcnt[0][e], c1 = wcnt[1][e], c2 = wcnt[2][e], c3 = wcnt[3][e];
    int base = atomicAdd(&cnt[e], c0 + c1 + c2 + c3);
    woff[0][e] = base;
    woff[1][e] = base + c0;
    woff[2][e] = base + c0 + c1;
    woff[3][e] = base + c0 + c1 + c2;
  }
  __syncthreads();
  rank[2 * t] = woff[wid][e0] + r0;
  rank[2 * t + 1] = woff[wid][e1] + r1;
}

__global__ void k_offsets(const int* __restrict__ cnt, int* __restrict__ off) {
  if (threadIdx.x == 0) {
    int s = 0;
    for (int e = 0; e < NE; e++) { off[e] = s; s += cnt[e]; }
  }
}

__global__ __launch_bounds__(256) void k_scatter(const int* __restrict__ off,
                                                 const int* __restrict__ esel,
                                                 const int* __restrict__ rank,
                                                 int* __restrict__ tok_of_slot,
                                                 int* __restrict__ slot_of_tok) {
  int t = blockIdx.x * 256 + threadIdx.x;
#pragma unroll
  for (int j = 0; j < 2; j++) {
    int e = esel[2 * t + j];
    int s = off[e] + rank[2 * t + j];
    tok_of_slot[s] = t;
    slot_of_tok[2 * t + j] = s;
  }
}

// ============ 256x128-tile BK=32 grouped GEMM, 3-ring counted-vmcnt ============
// R1 structure (proven 0-conflict 16x16x32 fragment reads, 2 barriers/tile,
// 2 blocks/CU) + XCD-locality remap:
//   flat grid; lid -> bijective chunked swizzle (m204): XCD c = lid&7 processes
//   expert c only, panels (ntile) sequential, mtile fastest. The 8 active
//   m-tile blocks sharing a 256KB B-panel become consecutive on one XCD ->
//   panel fetched once from HBM, 7x L2 hits; A-gather rows (~4MB/expert) stay
//   XCD-local with 16x reuse; FFN2 reads h written by the same XCD.
// FFN1=1: A = xb gathered via tok_of_slot, B = wcat (128-row group = 64 W1 +
//         64 W3 col pairs), epilogue silu(a1)*a3 -> h (64 cols/blk)
// FFN1=0: A = h (slot rows), B = w2t, epilogue -> y (128 cols/blk)
template<int FFN1>
__global__ __launch_bounds__(512, 4) void k_ffn(const short* __restrict__ Abase,
                                                const short* __restrict__ Bbase,
                                                const int* __restrict__ cnt,
                                                const int* __restrict__ off,
                                                const int* __restrict__ tok_of_slot,
                                                short* __restrict__ outp) {
  const int NT = FFN1 ? 16 : 8;        // ntiles per expert
  const int lid = blockIdx.x;          // flat grid: 32*8*NT blocks
  const int q = 32 * NT;               // blocks per XCD (total/8)
  const int swz = (lid & 7) * q + (lid >> 3);
  const int mt = swz & 31;
  const int pnl = swz >> 5;
  const int e = pnl / NT;              // == lid&7 : one expert per XCD
  const int nt = pnl % NT;

  const int cnt_e = cnt[e];
  const int m0 = mt * 256;
  if (m0 >= cnt_e) return;
  const int bse = off[e];
  const int n0 = nt * 128;
  const short* Bt = Bbase + (size_t)e * ((FFN1 ? 2048 : 1024) * 1024) + (size_t)n0 * 1024;

  // one k-tile: A 256x32 bf16 = 16 KB (8192 shorts), B 128x32 = 8 KB (4096)
  __shared__ __align__(128) short Al[3][8192];  // 48 KB
  __shared__ __align__(128) short Bl[3][4096];  // 24 KB  (72 KB total/block)

  const int tid = threadIdx.x;
  const int lane = tid & 63, wid = tid >> 6;
  const int wr = wid >> 1, wcn = wid & 1;

  // staging sources: chunk ch; row r = ch>>2; src col-chunk
  // c = (ch&3) ^ ((r>>1)&3)  (inverse-swizzled source, linear LDS dest)
  const short* srcA0; const short* srcA1; const short* srcB0;
  {
    int r0 = tid >> 2, c0 = (tid & 3) ^ ((r0 >> 1) & 3);
    int row0 = m0 + r0; if (row0 >= cnt_e) row0 = cnt_e - 1;
    long ar0 = FFN1 ? (long)tok_of_slot[bse + row0] : (long)(bse + row0);
    srcA0 = Abase + ar0 * 1024 + c0 * 8;
    int ch1 = tid + 512;
    int r1 = ch1 >> 2, c1 = (ch1 & 3) ^ ((r1 >> 1) & 3);
    int row1 = m0 + r1; if (row1 >= cnt_e) row1 = cnt_e - 1;
    long ar1 = FFN1 ? (long)tok_of_slot[bse + row1] : (long)(bse + row1);
    srcA1 = Abase + ar1 * 1024 + c1 * 8;
    srcB0 = Bt + (size_t)r0 * 1024 + c0 * 8;   // r0 < 128 for tid < 512
  }
  const int lA0 = wid * 512, lA1 = wid * 512 + 4096, lB0 = wid * 512;

  // fragment LDS byte offsets (swizzled read side) — proven 0-conflict pattern
  int aoff[4], boff[4];
#pragma unroll
  for (int m = 0; m < 4; m++) {
    int r = wr * 64 + m * 16 + (lane & 15);
    aoff[m] = (r * 4 + ((lane >> 4) ^ ((r >> 1) & 3))) * 16;
  }
#pragma unroll
  for (int n = 0; n < 4; n++) {
    int rb = FFN1 ? (wcn * 32 + (n & 1) * 16 + (n >> 1) * 64 + (lane & 15))
                  : (wcn * 64 + n * 16 + (lane & 15));
    boff[n] = (rb * 4 + ((lane >> 4) ^ ((rb >> 1) & 3))) * 16;
  }

  f32x4 acc[4][4];
#pragma unroll
  for (int m = 0; m < 4; m++)
#pragma unroll
    for (int n = 0; n < 4; n++) acc[m][n] = (f32x4){0.f, 0.f, 0.f, 0.f};

#define STG_A(b, kt) { gl_lds(srcA0 + (kt) * 32, &Al[b][lA0]); \
                       gl_lds(srcA1 + (kt) * 32, &Al[b][lA1]); }
#define STG_B(b, kt) { gl_lds(srcB0 + (kt) * 32, &Bl[b][lB0]); }

  // prologue: tiles 0,1 issued (3 loads each); wait tile 0 (tile 1 in flight)
  STG_A(0, 0); STG_B(0, 0);
  STG_A(1, 1); STG_B(1, 1);
  asm volatile("s_waitcnt vmcnt(3)" ::: "memory");
  __builtin_amdgcn_s_barrier();

  int cur = 0, nxt = 2;
  for (int t = 0; t < 32; ++t) {
    int ktn = (t + 2 < 32) ? (t + 2) : 31;  // clamped dup-stage: same bytes, benign
    const char* Ab = (const char*)Al[cur];
    const char* Bb = (const char*)Bl[cur];
    short8 a[4], b[4];
#pragma unroll
    for (int m = 0; m < 4; m++) a[m] = *(const short8*)(Ab + aoff[m]);
#pragma unroll
    for (int n = 0; n < 4; n++) b[n] = *(const short8*)(Bb + boff[n]);
    STG_A(nxt, ktn); STG_B(nxt, ktn);
    __builtin_amdgcn_s_barrier();
    __builtin_amdgcn_s_setprio(1);
#pragma unroll
    for (int m = 0; m < 4; m++)
#pragma unroll
      for (int n = 0; n < 4; n++)
        acc[m][n] = __builtin_amdgcn_mfma_f32_16x16x32_bf16(a[m], b[n], acc[m][n], 0, 0, 0);
    __builtin_amdgcn_s_setprio(0);
    asm volatile("s_waitcnt vmcnt(3)" ::: "memory");  // tile t+1 arrived; t+2 in flight
    __builtin_amdgcn_s_barrier();
    cur = (cur == 2) ? 0 : cur + 1;
    nxt = (nxt == 2) ? 0 : nxt + 1;
  }
  asm volatile("s_waitcnt vmcnt(0)" ::: "memory");  // drain before LDS dealloc

  // ---- epilogue ----
  if (FFN1) {
#pragma unroll
    for (int m = 0; m < 4; m++)
#pragma unroll
      for (int cc = 0; cc < 2; cc++) {
        f32x4 v1 = acc[m][cc], v3 = acc[m][cc + 2];
        int col = nt * 64 + wcn * 32 + cc * 16 + (lane & 15);
#pragma unroll
        for (int i = 0; i < 4; i++) {
          int row = m0 + wr * 64 + m * 16 + ((lane >> 4) * 4) + i;
          if (row < cnt_e) {
            float a1v = v1[i];
            float hv = (a1v / (1.f + __expf(-a1v))) * v3[i];
            outp[(size_t)(bse + row) * DE + col] = (short)f2bf(hv);
          }
        }
      }
  } else {
#pragma unroll
    for (int m = 0; m < 4; m++)
#pragma unroll
      for (int n = 0; n < 4; n++) {
        f32x4 v = acc[m][n];
        int col = n0 + wcn * 64 + n * 16 + (lane & 15);
#pragma unroll
        for (int i = 0; i < 4; i++) {
          int row = m0 + wr * 64 + m * 16 + ((lane >> 4) * 4) + i;
          if (row < cnt_e)
            outp[(size_t)(bse + row) * DM + col] = (short)f2bf(v[i]);
        }
      }
  }
}

// ---------------- combine: out[t] = w0*y[s0] + w1*y[s1] ----------------
__global__ __launch_bounds__(256) void k_combine(const short* __restrict__ y,
                                                 const int* __restrict__ slot_of_tok,
                                                 const float* __restrict__ wgt,
                                                 float* __restrict__ out) {
  int t = blockIdx.x;
  int s0 = slot_of_tok[2 * t], s1 = slot_of_tok[2 * t + 1];
  float w0 = wgt[2 * t], w1 = wgt[2 * t + 1];
  int c = threadIdx.x * 4;
  short4v a = *(const short4v*)(y + (size_t)s0 * DM + c);
  short4v b = *(const short4v*)(y + (size_t)s1 * DM + c);
  f32x4 o;
#pragma unroll
  for (int j = 0; j < 4; j++)
    o[j] = w0 * bf2f((unsigned short)a[j]) + w1 * bf2f((unsigned short)b[j]);
  *(f32x4*)(out + (size_t)t * DM + c) = o;
}

extern "C" void kernel_launch(void* const* d_in, const int* in_sizes, int n_in,
                              void* d_out, int out_size, void* d_ws, size_t ws_size,
                              hipStream_t stream) {
  const float* x  = (const float*)d_in[0];
  const float* Wr = (const float*)d_in[1];
  const float* W1 = (const float*)d_in[2];
  const float* W2 = (const float*)d_in[3];
  const float* W3 = (const float*)d_in[4];
  float* out = (float*)d_out;
  char* ws = (char*)d_ws;

  short* xb   = (short*)(ws);                   // 16 MB
  short* wcat = (short*)(ws + 16777216);        // 32 MB (8 x 2048 x 1024 bf16)
  short* w2t  = (short*)(ws + 50331648);        // 16 MB
  short* h    = (short*)(ws + 67108864);        // 32 MB
  short* y    = (short*)(ws + 100663296);       // 32 MB
  char* meta = ws + 134217728;
  int* cnt          = (int*)(meta);
  int* off          = (int*)(meta + 256);
  int* esel         = (int*)(meta + 512);
  int* rank         = (int*)(meta + 512 + 65536);
  int* tok_of_slot  = (int*)(meta + 512 + 2 * 65536);
  int* slot_of_tok  = (int*)(meta + 512 + 3 * 65536);
  float* wgt        = (float*)(meta + 512 + 4 * 65536);

  hipMemsetAsync(cnt, 0, 32, stream);
  k_transw<<<dim3(16, 16, 24), 256, 0, stream>>>(W1, W2, W3, wcat, w2t);
  k_router<<<2048, 256, 0, stream>>>(x, Wr, xb, esel, wgt);
  k_rank<<<32, 256, 0, stream>>>(esel, cnt, rank);
  k_offsets<<<1, 64, 0, stream>>>(cnt, off);
  k_scatter<<<32, 256, 0, stream>>>(off, esel, rank, tok_of_slot, slot_of_tok);
  k_ffn<1><<<dim3(32 * 8 * 16), 512, 0, stream>>>(xb, wcat, cnt, off, tok_of_slot, h);
  k_ffn<0><<<dim3(32 * 8 * 8), 512, 0, stream>>>(h, w2t, cnt, off, tok_of_slot, y);
  k_combine<<<8192, 256, 0, stream>>>(y, slot_of_tok, wgt, out);
}